// Round 1
// baseline (546.146 us; speedup 1.0000x reference)
//
#include <hip/hip_runtime.h>
#include <math.h>

// Problem constants
static constexpr int Bn   = 32;
static constexpr int Tn   = 512;
static constexpr int Cn   = 128;
static constexpr int Kk   = 3;
static constexpr int NLAG = 57;   // lags 8..64 inclusive
static constexpr int CYC  = 64;   // CYC_MAX
static constexpr int KWn  = 9;

// ---------------------------------------------------------------------------
// K1: circular autocorrelation (lags 8..64), top-3, softmax weights, Gamma.
// One block per batch b. Register ring buffer: 8-t block reuses rows across
// all 57 lags with 1 new float4 load per lag.
// ---------------------------------------------------------------------------
__global__ __launch_bounds__(256) void k_autocorr(const float* __restrict__ x,
    int* __restrict__ p_idx, float* __restrict__ wv, float* __restrict__ gval) {
  const int b   = blockIdx.x;
  const int tid = threadIdx.x;
  const float4* X4 = (const float4*)(x + (size_t)b * Tn * Cn);  // [512][32] float4

  float acc[NLAG];
#pragma unroll
  for (int i = 0; i < NLAG; ++i) acc[i] = 0.f;

  for (int it = 0; it < 8; ++it) {          // 2048 tasks / 256 threads
    const int id = it * 256 + tid;
    const int c4 = id & 31;
    const int t0 = (id >> 5) * 8;           // t-block of 8
    float4 A[8];
#pragma unroll
    for (int j = 0; j < 8; ++j) A[j] = X4[(t0 + j) * 32 + c4];
    float4 R[8];                             // ring: row t0+8+m at slot m&7
#pragma unroll
    for (int j = 0; j < 8; ++j) R[j] = X4[((t0 + 8 + j) & 511) * 32 + c4];
#pragma unroll
    for (int L = 0; L < NLAG; ++L) {        // lag = 8 + L
#pragma unroll
      for (int j = 0; j < 8; ++j) {
        float4 r = R[(L + j) & 7];
        float4 a = A[j];
        acc[L] += a.x * r.x + a.y * r.y + a.z * r.z + a.w * r.w;
      }
      if (L < 56) R[L & 7] = X4[((t0 + 16 + L) & 511) * 32 + c4];
    }
  }

  // reduce across 64 lanes then 4 waves
  __shared__ float lds_r[4][NLAG];
  __shared__ float rs[NLAG];
  const int lane = tid & 63, wave = tid >> 6;
#pragma unroll
  for (int i = 0; i < NLAG; ++i) {
    float v = acc[i];
#pragma unroll
    for (int m = 32; m > 0; m >>= 1) v += __shfl_xor(v, m, 64);
    if (lane == 0) lds_r[wave][i] = v;
  }
  __syncthreads();
  if (tid < NLAG)
    rs[tid] = (lds_r[0][tid] + lds_r[1][tid] + lds_r[2][tid] + lds_r[3][tid]) * (1.0f / Cn);
  __syncthreads();

  if (tid == 0) {
    float tmp[NLAG];
    for (int i = 0; i < NLAG; ++i) tmp[i] = rs[i];
    float vals[Kk]; int lags[Kk];
    for (int k = 0; k < Kk; ++k) {
      float best = -INFINITY; int bi = 0;
      for (int i = 0; i < NLAG; ++i)
        if (tmp[i] > best) { best = tmp[i]; bi = i; }   // strict > == topk tie rule
      vals[k] = best; lags[k] = bi + 8; tmp[bi] = -INFINITY;
    }
    const float m  = vals[0];
    const float e0 = expf(vals[0] - m), e1 = expf(vals[1] - m), e2 = expf(vals[2] - m);
    const float s  = e0 + e1 + e2;
    const float w0 = e0 / s, w1 = e1 / s, w2 = e2 / s;
    p_idx[b * 3 + 0] = lags[0]; p_idx[b * 3 + 1] = lags[1]; p_idx[b * 3 + 2] = lags[2];
    wv[b * 3 + 0] = w0; wv[b * 3 + 1] = w1; wv[b * 3 + 2] = w2;
    const float H  = -(w0 * logf(w0 + 1e-8f) + w1 * logf(w1 + 1e-8f) + w2 * logf(w2 + 1e-8f));
    const float lg = logf(3.0f + 1e-8f) + 1e-8f;
    float G = 1.0f - H / lg;
    gval[b] = fminf(fmaxf(G, 0.0f), 1.0f);
  }
}

// ---------------------------------------------------------------------------
// K2: fold -> u[n,l,c] = (1/64) * sum_{j<p} x[b, refl(l*p+j), c]  (0 if l>=ncyc)
// grid (l=64, n=96), 128 threads over c.
// ---------------------------------------------------------------------------
__global__ __launch_bounds__(128) void k_fold_u(const float* __restrict__ x,
    const int* __restrict__ p_idx, float* __restrict__ u) {
  const int l = blockIdx.x;
  const int n = blockIdx.y;
  const int c = threadIdx.x;
  const int p = p_idx[n];
  const int ncyc = (Tn + p - 1) / p;
  float acc = 0.f;
  if (l < ncyc) {
    const float* xb = x + (size_t)(n / 3) * Tn * Cn;
    const int base = l * p;
    for (int j = 0; j < p; ++j) {
      const int time = base + j;                       // < 576 always
      const int src = time < Tn ? time : (2 * (Tn - 1) - time);  // reflect
      acc += xb[src * Cn + c];
    }
  }
  u[((size_t)n * CYC + l) * Cn + c] = acc * (1.0f / 64.0f);
}

// ---------------------------------------------------------------------------
// K3: dwconv(9) over cyc + pointwise 128x128 + GroupNorm(32) + gelu + gate.
// One block per n (96 blocks), 256 threads.
// ---------------------------------------------------------------------------
__global__ __launch_bounds__(256) void k_cycconv(
    const float* __restrict__ u, const float* __restrict__ Wdw,
    const float* __restrict__ Wpw, const float* __restrict__ gnw,
    const float* __restrict__ gnb, const float* __restrict__ Wgate,
    float* __restrict__ hh) {
  const int n = blockIdx.x;
  const int tid = threadIdx.x;
  const float* un = u + (size_t)n * CYC * Cn;   // [64][128]

  __shared__ float ubar_s[Cn];
  __shared__ float gates[Cn];
  __shared__ float h1s[Cn][65];                 // pad 65: lanes-over-l reads conflict-free

  // ubar[c] = mean over l
  if (tid < Cn) {
    float s = 0.f;
    for (int l = 0; l < CYC; ++l) s += un[l * Cn + tid];
    ubar_s[tid] = s * (1.0f / CYC);
  }
  __syncthreads();

  // gate[o] = sigmoid(Wgate[o,:] . ubar)
  if (tid < Cn) {
    float z = 0.f;
    for (int c = 0; c < Cn; ++c) z += Wgate[tid * Cn + c] * ubar_s[c];
    gates[tid] = 1.0f / (1.0f + expf(-z));
  }

  // depthwise conv: thread (c = tid&127, lh = tid>>7), 32 l each
  {
    const int c = tid & 127, lh = tid >> 7;
    float wk[KWn];
#pragma unroll
    for (int k = 0; k < KWn; ++k) wk[k] = Wdw[c * KWn + k];
    for (int l = lh * 32; l < lh * 32 + 32; ++l) {
      float s = 0.f;
#pragma unroll
      for (int k = 0; k < KWn; ++k) {
        const int ll = l + k - KWn / 2;
        if (ll >= 0 && ll < CYC) s += un[ll * Cn + c] * wk[k];
      }
      h1s[c][l] = s;
    }
  }
  __syncthreads();

  // pointwise: wave og handles o in [og*32, og*32+32), lane = l.
  const int l  = tid & 63;
  const int og = __builtin_amdgcn_readfirstlane(tid >> 6);  // wave-uniform -> s_loads
  float acc[32];
#pragma unroll
  for (int i = 0; i < 32; ++i) acc[i] = 0.f;
  const float* wbase = Wpw + og * 32 * Cn;
  for (int c = 0; c < Cn; ++c) {
    const float hv = h1s[c][l];
#pragma unroll
    for (int i = 0; i < 32; ++i) acc[i] = fmaf(wbase[i * Cn + c], hv, acc[i]);
  }

  // GroupNorm stats: groups of 4 channels x 64 l. 8 groups per wave, all 4 ch
  // in-thread, all 64 l across lanes.
  float s1[8], s2[8];
#pragma unroll
  for (int g = 0; g < 8; ++g) { s1[g] = 0.f; s2[g] = 0.f; }
#pragma unroll
  for (int i = 0; i < 32; ++i) {
    s1[i >> 2] += acc[i];
    s2[i >> 2] += acc[i] * acc[i];
  }
#pragma unroll
  for (int g = 0; g < 8; ++g) {
#pragma unroll
    for (int m = 32; m > 0; m >>= 1) {
      s1[g] += __shfl_xor(s1[g], m, 64);
      s2[g] += __shfl_xor(s2[g], m, 64);
    }
  }

  __syncthreads();  // everyone done reading h1s; safe to overwrite

  // normalize + gelu + gate, store back to h1s[o][l]
#pragma unroll
  for (int i = 0; i < 32; ++i) {
    const int o = og * 32 + i;
    const int g = i >> 2;
    const float mean = s1[g] * (1.0f / 256.0f);
    const float var  = s2[g] * (1.0f / 256.0f) - mean * mean;
    float h = (acc[i] - mean) * rsqrtf(var + 1e-5f);
    h = h * gnw[o] + gnb[o];
    h = 0.5f * h * (1.0f + erff(h * 0.70710678118654752440f));  // exact gelu
    h1s[o][l] = h * gates[o];
  }
  __syncthreads();

  // coalesced store: hh layout (n, l, c)
  float* hhn = hh + (size_t)n * CYC * Cn;
  for (int idx = tid; idx < CYC * Cn; idx += 256) {
    const int l2 = idx >> 7;
    const int c2 = idx & 127;
    hhn[idx] = h1s[c2][l2];
  }
}

// ---------------------------------------------------------------------------
// K4: fused epilogue. periodic = sw*x + d, d = gamma_c * sum_k w_k hh[nk,t/pk,c];
// num/den per (b,c) over t; out = x - g*(num/den)*periodic.
// One block per b, 512 threads (c=tid&127, q=tid>>7 covers t).
// ---------------------------------------------------------------------------
__global__ __launch_bounds__(512) void k_final(const float* __restrict__ x,
    const float* __restrict__ hh, const int* __restrict__ p_idx,
    const float* __restrict__ wv, const float* __restrict__ gval,
    const float* __restrict__ gamma, float* __restrict__ out) {
  const int b = blockIdx.x;
  const int tid = threadIdx.x;
  __shared__ unsigned short cycs[Tn][Kk];
  __shared__ float redn[4][Cn], redd[4][Cn], scale_s[Cn];

  const int p0 = p_idx[b * 3 + 0], p1 = p_idx[b * 3 + 1], p2 = p_idx[b * 3 + 2];
  const float w0 = wv[b * 3 + 0], w1 = wv[b * 3 + 1], w2 = wv[b * 3 + 2];
  const float sw = w0 + w1 + w2;
  const float g = gval[b];

  if (tid < Tn) {
    cycs[tid][0] = (unsigned short)(tid / p0);
    cycs[tid][1] = (unsigned short)(tid / p1);
    cycs[tid][2] = (unsigned short)(tid / p2);
  }
  __syncthreads();

  const int c = tid & 127, q = tid >> 7;
  const float gam = gamma[c];
  const float* hh0 = hh + ((size_t)(b * 3 + 0) * CYC) * Cn + c;
  const float* hh1 = hh + ((size_t)(b * 3 + 1) * CYC) * Cn + c;
  const float* hh2 = hh + ((size_t)(b * 3 + 2) * CYC) * Cn + c;
  const float* xb = x + (size_t)b * Tn * Cn;

  float na = 0.f, da = 0.f;
  for (int t = q * 128; t < q * 128 + 128; ++t) {
    const float xv = xb[t * Cn + c];
    const float dv = gam * (w0 * hh0[cycs[t][0] * Cn] +
                            w1 * hh1[cycs[t][1] * Cn] +
                            w2 * hh2[cycs[t][2] * Cn]);
    const float P = sw * xv + dv;
    const float loc = xv - P;
    na += loc * P;
    da += P * P;
  }
  redn[q][c] = na; redd[q][c] = da;
  __syncthreads();
  if (tid < Cn) {
    const float num = redn[0][tid] + redn[1][tid] + redn[2][tid] + redn[3][tid];
    const float den = redd[0][tid] + redd[1][tid] + redd[2][tid] + redd[3][tid] + 1e-6f;
    scale_s[tid] = g * (num / den);
  }
  __syncthreads();

  const float sc = scale_s[c];
  float* ob = out + (size_t)b * Tn * Cn;
  for (int t = q * 128; t < q * 128 + 128; ++t) {
    const float xv = xb[t * Cn + c];
    const float dv = gam * (w0 * hh0[cycs[t][0] * Cn] +
                            w1 * hh1[cycs[t][1] * Cn] +
                            w2 * hh2[cycs[t][2] * Cn]);
    const float P = sw * xv + dv;
    ob[t * Cn + c] = xv - sc * P;
  }
}

// ---------------------------------------------------------------------------
extern "C" void kernel_launch(void* const* d_in, const int* in_sizes, int n_in,
                              void* d_out, int out_size, void* d_ws, size_t ws_size,
                              hipStream_t stream) {
  const float* x     = (const float*)d_in[0];
  const float* Wdw   = (const float*)d_in[1];
  const float* Wpw   = (const float*)d_in[2];
  const float* gnw   = (const float*)d_in[3];
  const float* gnb   = (const float*)d_in[4];
  const float* Wgate = (const float*)d_in[5];
  const float* gamma = (const float*)d_in[6];
  float* out = (float*)d_out;

  char* ws = (char*)d_ws;
  int*   p_idx = (int*)ws;                    // 96 ints
  float* wvp   = (float*)(ws + 512);          // 96 floats
  float* gvalp = (float*)(ws + 1024);         // 32 floats
  float* u     = (float*)(ws + 4096);                          // 96*64*128 f32 (3 MB)
  float* hh    = (float*)(ws + 4096 + (size_t)96 * 64 * 128 * 4);  // 3 MB

  k_autocorr<<<Bn, 256, 0, stream>>>(x, p_idx, wvp, gvalp);
  k_fold_u<<<dim3(CYC, Bn * Kk), 128, 0, stream>>>(x, p_idx, u);
  k_cycconv<<<Bn * Kk, 256, 0, stream>>>(u, Wdw, Wpw, gnw, gnb, Wgate, hh);
  k_final<<<Bn, 512, 0, stream>>>(x, hh, p_idx, wvp, gvalp, gamma, out);
}

// Round 2
// 235.232 us; speedup vs baseline: 2.3217x; 2.3217x over previous
//
#include <hip/hip_runtime.h>
#include <math.h>

// Problem constants
static constexpr int Bn   = 32;
static constexpr int Tn   = 512;
static constexpr int Cn   = 128;
static constexpr int Kk   = 3;
static constexpr int NLAG = 57;   // lags 8..64 inclusive
static constexpr int CYC  = 64;   // CYC_MAX
static constexpr int KWn  = 9;

// ---------------------------------------------------------------------------
// K1: circular autocorrelation partials. Block = (b, lag-group of 8).
// Per thread: A[8] rows + R[16]-row window covers all 8 lags of the group.
// acc[8] only -> ~110 VGPR, no spill (R1 spilled at 256 VGPR / 35MB scratch).
// ---------------------------------------------------------------------------
__global__ __launch_bounds__(256) void k_autocorr(const float* __restrict__ x,
    float* __restrict__ r_ws) {
  const int b   = blockIdx.x >> 3;
  const int grp = blockIdx.x & 7;
  const int L0  = 8 + grp * 8;              // first lag of this group
  const int tid = threadIdx.x;
  const float4* X4 = (const float4*)(x + (size_t)b * Tn * Cn);  // [512][32]

  float acc[8];
#pragma unroll
  for (int i = 0; i < 8; ++i) acc[i] = 0.f;

  for (int it = 0; it < 8; ++it) {          // 2048 (t-block, c4) tasks / 256 thr
    const int id = it * 256 + tid;
    const int c4 = id & 31;
    const int t0 = (id >> 5) * 8;
    float4 A[8];
#pragma unroll
    for (int j = 0; j < 8; ++j) A[j] = X4[(t0 + j) * 32 + c4];
    float4 R[16];                           // rows t0+L0 .. t0+L0+15 (circular)
#pragma unroll
    for (int j = 0; j < 16; ++j) R[j] = X4[((t0 + L0 + j) & 511) * 32 + c4];
#pragma unroll
    for (int g = 0; g < 8; ++g) {           // lag = L0 + g
#pragma unroll
      for (int j = 0; j < 8; ++j) {
        const float4 a = A[j];
        const float4 r = R[g + j];          // g+j <= 14
        acc[g] += a.x * r.x + a.y * r.y + a.z * r.z + a.w * r.w;
      }
    }
  }

  // reduce across 64 lanes then 4 waves
  __shared__ float lds_r[4][8];
  const int lane = tid & 63, wave = tid >> 6;
#pragma unroll
  for (int g = 0; g < 8; ++g) {
    float v = acc[g];
#pragma unroll
    for (int m = 32; m > 0; m >>= 1) v += __shfl_xor(v, m, 64);
    if (lane == 0) lds_r[wave][g] = v;
  }
  __syncthreads();
  if (tid < 8) {
    const int li = grp * 8 + tid;           // lag index (lag-8)
    if (li < NLAG) {
      r_ws[b * NLAG + li] =
          (lds_r[0][tid] + lds_r[1][tid] + lds_r[2][tid] + lds_r[3][tid]) * (1.0f / Cn);
    }
  }
}

// ---------------------------------------------------------------------------
// K1b: top-3 + softmax + Gamma per batch. 32 blocks x 64 threads (trivial).
// ---------------------------------------------------------------------------
__global__ __launch_bounds__(64) void k_topk(const float* __restrict__ r_ws,
    int* __restrict__ p_idx, float* __restrict__ wv, float* __restrict__ gval) {
  const int b = blockIdx.x;
  const int tid = threadIdx.x;
  __shared__ float rs[NLAG];
  if (tid < NLAG) rs[tid] = r_ws[b * NLAG + tid];
  __syncthreads();
  if (tid == 0) {
    float tmp[NLAG];
    for (int i = 0; i < NLAG; ++i) tmp[i] = rs[i];
    float vals[Kk]; int lags[Kk];
    for (int k = 0; k < Kk; ++k) {
      float best = -INFINITY; int bi = 0;
      for (int i = 0; i < NLAG; ++i)
        if (tmp[i] > best) { best = tmp[i]; bi = i; }   // first-max == topk tie rule
      vals[k] = best; lags[k] = bi + 8; tmp[bi] = -INFINITY;
    }
    const float m  = vals[0];
    const float e0 = expf(vals[0] - m), e1 = expf(vals[1] - m), e2 = expf(vals[2] - m);
    const float s  = e0 + e1 + e2;
    const float w0 = e0 / s, w1 = e1 / s, w2 = e2 / s;
    p_idx[b * 3 + 0] = lags[0]; p_idx[b * 3 + 1] = lags[1]; p_idx[b * 3 + 2] = lags[2];
    wv[b * 3 + 0] = w0; wv[b * 3 + 1] = w1; wv[b * 3 + 2] = w2;
    const float H  = -(w0 * logf(w0 + 1e-8f) + w1 * logf(w1 + 1e-8f) + w2 * logf(w2 + 1e-8f));
    const float lg = logf(3.0f + 1e-8f) + 1e-8f;
    float G = 1.0f - H / lg;
    gval[b] = fminf(fmaxf(G, 0.0f), 1.0f);
  }
}

// ---------------------------------------------------------------------------
// K2: fold -> u[n,l,c] = (1/64) * sum_{j<p} x[b, refl(l*p+j), c]  (0 if l>=ncyc)
// grid (l=64, n=96), 128 threads over c.
// ---------------------------------------------------------------------------
__global__ __launch_bounds__(128) void k_fold_u(const float* __restrict__ x,
    const int* __restrict__ p_idx, float* __restrict__ u) {
  const int l = blockIdx.x;
  const int n = blockIdx.y;
  const int c = threadIdx.x;
  const int p = p_idx[n];
  const int ncyc = (Tn + p - 1) / p;
  float acc = 0.f;
  if (l < ncyc) {
    const float* xb = x + (size_t)(n / 3) * Tn * Cn;
    const int base = l * p;
    for (int j = 0; j < p; ++j) {
      const int time = base + j;                       // < 576 always
      const int src = time < Tn ? time : (2 * (Tn - 1) - time);  // reflect
      acc += xb[src * Cn + c];
    }
  }
  u[((size_t)n * CYC + l) * Cn + c] = acc * (1.0f / 64.0f);
}

// ---------------------------------------------------------------------------
// K3: dwconv(9) over cyc + pointwise 128x128 + GroupNorm(32) + gelu + gate.
// One block per n (96 blocks), 256 threads.
// ---------------------------------------------------------------------------
__global__ __launch_bounds__(256) void k_cycconv(
    const float* __restrict__ u, const float* __restrict__ Wdw,
    const float* __restrict__ Wpw, const float* __restrict__ gnw,
    const float* __restrict__ gnb, const float* __restrict__ Wgate,
    float* __restrict__ hh) {
  const int n = blockIdx.x;
  const int tid = threadIdx.x;
  const float* un = u + (size_t)n * CYC * Cn;   // [64][128]

  __shared__ float ubar_s[Cn];
  __shared__ float gates[Cn];
  __shared__ float h1s[Cn][65];                 // pad 65: lanes-over-l reads conflict-free

  // ubar[c] = mean over l
  if (tid < Cn) {
    float s = 0.f;
    for (int l = 0; l < CYC; ++l) s += un[l * Cn + tid];
    ubar_s[tid] = s * (1.0f / CYC);
  }
  __syncthreads();

  // gate[o] = sigmoid(Wgate[o,:] . ubar)
  if (tid < Cn) {
    float z = 0.f;
    for (int c = 0; c < Cn; ++c) z += Wgate[tid * Cn + c] * ubar_s[c];
    gates[tid] = 1.0f / (1.0f + expf(-z));
  }

  // depthwise conv: thread (c = tid&127, lh = tid>>7), 32 l each
  {
    const int c = tid & 127, lh = tid >> 7;
    float wk[KWn];
#pragma unroll
    for (int k = 0; k < KWn; ++k) wk[k] = Wdw[c * KWn + k];
    for (int l = lh * 32; l < lh * 32 + 32; ++l) {
      float s = 0.f;
#pragma unroll
      for (int k = 0; k < KWn; ++k) {
        const int ll = l + k - KWn / 2;
        if (ll >= 0 && ll < CYC) s += un[ll * Cn + c] * wk[k];
      }
      h1s[c][l] = s;
    }
  }
  __syncthreads();

  // pointwise: wave og handles o in [og*32, og*32+32), lane = l.
  const int l  = tid & 63;
  const int og = __builtin_amdgcn_readfirstlane(tid >> 6);  // wave-uniform -> s_loads
  float acc[32];
#pragma unroll
  for (int i = 0; i < 32; ++i) acc[i] = 0.f;
  const float* wbase = Wpw + og * 32 * Cn;
  for (int c = 0; c < Cn; ++c) {
    const float hv = h1s[c][l];
#pragma unroll
    for (int i = 0; i < 32; ++i) acc[i] = fmaf(wbase[i * Cn + c], hv, acc[i]);
  }

  // GroupNorm stats: groups of 4 channels x 64 l. 8 groups per wave, all 4 ch
  // in-thread, all 64 l across lanes.
  float s1[8], s2[8];
#pragma unroll
  for (int g = 0; g < 8; ++g) { s1[g] = 0.f; s2[g] = 0.f; }
#pragma unroll
  for (int i = 0; i < 32; ++i) {
    s1[i >> 2] += acc[i];
    s2[i >> 2] += acc[i] * acc[i];
  }
#pragma unroll
  for (int g = 0; g < 8; ++g) {
#pragma unroll
    for (int m = 32; m > 0; m >>= 1) {
      s1[g] += __shfl_xor(s1[g], m, 64);
      s2[g] += __shfl_xor(s2[g], m, 64);
    }
  }

  __syncthreads();  // everyone done reading h1s; safe to overwrite

  // normalize + gelu + gate, store back to h1s[o][l]
#pragma unroll
  for (int i = 0; i < 32; ++i) {
    const int o = og * 32 + i;
    const int g = i >> 2;
    const float mean = s1[g] * (1.0f / 256.0f);
    const float var  = s2[g] * (1.0f / 256.0f) - mean * mean;
    float h = (acc[i] - mean) * rsqrtf(var + 1e-5f);
    h = h * gnw[o] + gnb[o];
    h = 0.5f * h * (1.0f + erff(h * 0.70710678118654752440f));  // exact gelu
    h1s[o][l] = h * gates[o];
  }
  __syncthreads();

  // coalesced store: hh layout (n, l, c)
  float* hhn = hh + (size_t)n * CYC * Cn;
  for (int idx = tid; idx < CYC * Cn; idx += 256) {
    const int l2 = idx >> 7;
    const int c2 = idx & 127;
    hhn[idx] = h1s[c2][l2];
  }
}

// ---------------------------------------------------------------------------
// K4: fused epilogue. periodic = sw*x + d, d = gamma_c * sum_k w_k hh[nk,t/pk,c];
// num/den per (b,c) over t; out = x - g*(num/den)*periodic.
// One block per b, 512 threads (c=tid&127, q=tid>>7 covers t).
// ---------------------------------------------------------------------------
__global__ __launch_bounds__(512) void k_final(const float* __restrict__ x,
    const float* __restrict__ hh, const int* __restrict__ p_idx,
    const float* __restrict__ wv, const float* __restrict__ gval,
    const float* __restrict__ gamma, float* __restrict__ out) {
  const int b = blockIdx.x;
  const int tid = threadIdx.x;
  __shared__ unsigned short cycs[Tn][Kk];
  __shared__ float redn[4][Cn], redd[4][Cn], scale_s[Cn];

  const int p0 = p_idx[b * 3 + 0], p1 = p_idx[b * 3 + 1], p2 = p_idx[b * 3 + 2];
  const float w0 = wv[b * 3 + 0], w1 = wv[b * 3 + 1], w2 = wv[b * 3 + 2];
  const float sw = w0 + w1 + w2;
  const float g = gval[b];

  if (tid < Tn) {
    cycs[tid][0] = (unsigned short)(tid / p0);
    cycs[tid][1] = (unsigned short)(tid / p1);
    cycs[tid][2] = (unsigned short)(tid / p2);
  }
  __syncthreads();

  const int c = tid & 127, q = tid >> 7;
  const float gam = gamma[c];
  const float* hh0 = hh + ((size_t)(b * 3 + 0) * CYC) * Cn + c;
  const float* hh1 = hh + ((size_t)(b * 3 + 1) * CYC) * Cn + c;
  const float* hh2 = hh + ((size_t)(b * 3 + 2) * CYC) * Cn + c;
  const float* xb = x + (size_t)b * Tn * Cn;

  float na = 0.f, da = 0.f;
  for (int t = q * 128; t < q * 128 + 128; ++t) {
    const float xv = xb[t * Cn + c];
    const float dv = gam * (w0 * hh0[cycs[t][0] * Cn] +
                            w1 * hh1[cycs[t][1] * Cn] +
                            w2 * hh2[cycs[t][2] * Cn]);
    const float P = sw * xv + dv;
    const float loc = xv - P;
    na += loc * P;
    da += P * P;
  }
  redn[q][c] = na; redd[q][c] = da;
  __syncthreads();
  if (tid < Cn) {
    const float num = redn[0][tid] + redn[1][tid] + redn[2][tid] + redn[3][tid];
    const float den = redd[0][tid] + redd[1][tid] + redd[2][tid] + redd[3][tid] + 1e-6f;
    scale_s[tid] = g * (num / den);
  }
  __syncthreads();

  const float sc = scale_s[c];
  float* ob = out + (size_t)b * Tn * Cn;
  for (int t = q * 128; t < q * 128 + 128; ++t) {
    const float xv = xb[t * Cn + c];
    const float dv = gam * (w0 * hh0[cycs[t][0] * Cn] +
                            w1 * hh1[cycs[t][1] * Cn] +
                            w2 * hh2[cycs[t][2] * Cn]);
    const float P = sw * xv + dv;
    ob[t * Cn + c] = xv - sc * P;
  }
}

// ---------------------------------------------------------------------------
extern "C" void kernel_launch(void* const* d_in, const int* in_sizes, int n_in,
                              void* d_out, int out_size, void* d_ws, size_t ws_size,
                              hipStream_t stream) {
  const float* x     = (const float*)d_in[0];
  const float* Wdw   = (const float*)d_in[1];
  const float* Wpw   = (const float*)d_in[2];
  const float* gnw   = (const float*)d_in[3];
  const float* gnb   = (const float*)d_in[4];
  const float* Wgate = (const float*)d_in[5];
  const float* gamma = (const float*)d_in[6];
  float* out = (float*)d_out;

  char* ws = (char*)d_ws;
  int*   p_idx = (int*)ws;                    // 96 ints
  float* wvp   = (float*)(ws + 512);          // 96 floats
  float* gvalp = (float*)(ws + 1024);         // 32 floats
  float* r_ws  = (float*)(ws + 2048);         // 32*57 floats (~7.3 KB)
  float* u     = (float*)(ws + 16384);                             // 3 MB
  float* hh    = (float*)(ws + 16384 + (size_t)96 * 64 * 128 * 4); // 3 MB

  k_autocorr<<<Bn * 8, 256, 0, stream>>>(x, r_ws);
  k_topk<<<Bn, 64, 0, stream>>>(r_ws, p_idx, wvp, gvalp);
  k_fold_u<<<dim3(CYC, Bn * Kk), 128, 0, stream>>>(x, p_idx, u);
  k_cycconv<<<Bn * Kk, 256, 0, stream>>>(u, Wdw, Wpw, gnw, gnb, Wgate, hh);
  k_final<<<Bn, 512, 0, stream>>>(x, hh, p_idx, wvp, gvalp, gamma, out);
}

// Round 3
// 164.982 us; speedup vs baseline: 3.3103x; 1.4258x over previous
//
#include <hip/hip_runtime.h>
#include <math.h>

// Problem constants
static constexpr int Bn   = 32;
static constexpr int Tn   = 512;
static constexpr int Cn   = 128;
static constexpr int Kk   = 3;
static constexpr int NLAG = 57;   // lags 8..64 inclusive
static constexpr int CYC  = 64;   // CYC_MAX
static constexpr int KWn  = 9;

// ---------------------------------------------------------------------------
// K1: circular autocorrelation partials. Block = (b, lag-group of 8).
// ---------------------------------------------------------------------------
__global__ __launch_bounds__(256) void k_autocorr(const float* __restrict__ x,
    float* __restrict__ r_ws) {
  const int b   = blockIdx.x >> 3;
  const int grp = blockIdx.x & 7;
  const int L0  = 8 + grp * 8;
  const int tid = threadIdx.x;
  const float4* X4 = (const float4*)(x + (size_t)b * Tn * Cn);  // [512][32]

  float acc[8];
#pragma unroll
  for (int i = 0; i < 8; ++i) acc[i] = 0.f;

  for (int it = 0; it < 8; ++it) {
    const int id = it * 256 + tid;
    const int c4 = id & 31;
    const int t0 = (id >> 5) * 8;
    float4 A[8];
#pragma unroll
    for (int j = 0; j < 8; ++j) A[j] = X4[(t0 + j) * 32 + c4];
    float4 R[16];
#pragma unroll
    for (int j = 0; j < 16; ++j) R[j] = X4[((t0 + L0 + j) & 511) * 32 + c4];
#pragma unroll
    for (int g = 0; g < 8; ++g) {
#pragma unroll
      for (int j = 0; j < 8; ++j) {
        const float4 a = A[j];
        const float4 r = R[g + j];
        acc[g] += a.x * r.x + a.y * r.y + a.z * r.z + a.w * r.w;
      }
    }
  }

  __shared__ float lds_r[4][8];
  const int lane = tid & 63, wave = tid >> 6;
#pragma unroll
  for (int g = 0; g < 8; ++g) {
    float v = acc[g];
#pragma unroll
    for (int m = 32; m > 0; m >>= 1) v += __shfl_xor(v, m, 64);
    if (lane == 0) lds_r[wave][g] = v;
  }
  __syncthreads();
  if (tid < 8) {
    const int li = grp * 8 + tid;
    if (li < NLAG) {
      r_ws[b * NLAG + li] =
          (lds_r[0][tid] + lds_r[1][tid] + lds_r[2][tid] + lds_r[3][tid]) * (1.0f / Cn);
    }
  }
}

// ---------------------------------------------------------------------------
// K1b: top-3 + softmax + Gamma per batch.
// ---------------------------------------------------------------------------
__global__ __launch_bounds__(64) void k_topk(const float* __restrict__ r_ws,
    int* __restrict__ p_idx, float* __restrict__ wv, float* __restrict__ gval) {
  const int b = blockIdx.x;
  const int tid = threadIdx.x;
  __shared__ float rs[NLAG];
  if (tid < NLAG) rs[tid] = r_ws[b * NLAG + tid];
  __syncthreads();
  if (tid == 0) {
    float tmp[NLAG];
    for (int i = 0; i < NLAG; ++i) tmp[i] = rs[i];
    float vals[Kk]; int lags[Kk];
    for (int k = 0; k < Kk; ++k) {
      float best = -INFINITY; int bi = 0;
      for (int i = 0; i < NLAG; ++i)
        if (tmp[i] > best) { best = tmp[i]; bi = i; }
      vals[k] = best; lags[k] = bi + 8; tmp[bi] = -INFINITY;
    }
    const float m  = vals[0];
    const float e0 = expf(vals[0] - m), e1 = expf(vals[1] - m), e2 = expf(vals[2] - m);
    const float s  = e0 + e1 + e2;
    const float w0 = e0 / s, w1 = e1 / s, w2 = e2 / s;
    p_idx[b * 3 + 0] = lags[0]; p_idx[b * 3 + 1] = lags[1]; p_idx[b * 3 + 2] = lags[2];
    wv[b * 3 + 0] = w0; wv[b * 3 + 1] = w1; wv[b * 3 + 2] = w2;
    const float H  = -(w0 * logf(w0 + 1e-8f) + w1 * logf(w1 + 1e-8f) + w2 * logf(w2 + 1e-8f));
    const float lg = logf(3.0f + 1e-8f) + 1e-8f;
    float G = 1.0f - H / lg;
    gval[b] = fminf(fmaxf(G, 0.0f), 1.0f);
  }
}

// ---------------------------------------------------------------------------
// K2: fold -> u[n,l,c] = (1/64) * sum_{j<p} x[b, refl(l*p+j), c]
// ---------------------------------------------------------------------------
__global__ __launch_bounds__(128) void k_fold_u(const float* __restrict__ x,
    const int* __restrict__ p_idx, float* __restrict__ u) {
  const int l = blockIdx.x;
  const int n = blockIdx.y;
  const int c = threadIdx.x;
  const int p = p_idx[n];
  const int ncyc = (Tn + p - 1) / p;
  float acc = 0.f;
  if (l < ncyc) {
    const float* xb = x + (size_t)(n / 3) * Tn * Cn;
    const int base = l * p;
    for (int j = 0; j < p; ++j) {
      const int time = base + j;
      const int src = time < Tn ? time : (2 * (Tn - 1) - time);
      acc += xb[src * Cn + c];
    }
  }
  u[((size_t)n * CYC + l) * Cn + c] = acc * (1.0f / 64.0f);
}

// ---------------------------------------------------------------------------
// K3 v2: grid (n=96, og=8). Block computes 16 output channels (= 4 GN groups).
// 256 threads = 4 waves; lane = l, wave wq handles o = og*16+wq*4 .. +4.
// LDS: one 8320-float buffer, u-view [64][129] then h1-view [128][65].
// ---------------------------------------------------------------------------
__global__ __launch_bounds__(256) void k_cycconv(
    const float* __restrict__ u, const float* __restrict__ Wdw,
    const float* __restrict__ Wpw, const float* __restrict__ gnw,
    const float* __restrict__ gnb, const float* __restrict__ Wgate,
    float* __restrict__ hh) {
  const int n  = blockIdx.x;
  const int og = blockIdx.y;
  const int tid = threadIdx.x;
  const int l  = tid & 63;
  const int wq = __builtin_amdgcn_readfirstlane(tid >> 6);  // wave-uniform

  __shared__ float smem[8320];     // u-view: [l][129]; h1-view: [c][65]
  __shared__ float ubar_s[Cn];
  __shared__ float gates_s[16];

  const float* un = u + (size_t)n * CYC * Cn;   // [64][128]

  // stage u into LDS (u-view, pad 129 -> conflict-free column reads)
  for (int i = 0; i < 32; ++i) {
    const int idx = i * 256 + tid;
    const int ll = idx >> 7, cc = idx & 127;
    smem[ll * 129 + cc] = un[idx];
  }
  __syncthreads();

  // ubar[c] (threads 0..127)
  if (tid < Cn) {
    float s = 0.f;
    for (int ll = 0; ll < CYC; ++ll) s += smem[ll * 129 + tid];
    ubar_s[tid] = s * (1.0f / CYC);
  }

  // depthwise conv -> registers: thread (l, wq) computes c = wq*32 .. +32
  float hreg[32];
  {
    const int c0 = wq * 32;
#pragma unroll
    for (int i = 0; i < 32; ++i) {
      const int c = c0 + i;
      float s = 0.f;
#pragma unroll
      for (int k = 0; k < KWn; ++k) {
        const int ll = l + k - KWn / 2;
        if (ll >= 0 && ll < CYC) s += smem[ll * 129 + c] * Wdw[c * KWn + k];
      }
      hreg[i] = s;
    }
  }
  __syncthreads();   // u-view reads done; ubar_s visible

  // gates for this block's 16 outputs (threads 0..15)
  if (tid < 16) {
    const int o = og * 16 + tid;
    float z = 0.f;
    for (int c = 0; c < Cn; ++c) z += Wgate[o * Cn + c] * ubar_s[c];
    gates_s[tid] = 1.0f / (1.0f + expf(-z));
  }

  // overwrite LDS with h1-view [c][65]
  {
    const int c0 = wq * 32;
#pragma unroll
    for (int i = 0; i < 32; ++i) smem[(c0 + i) * 65 + l] = hreg[i];
  }
  __syncthreads();

  // pointwise: 4 outputs per wave
  const int o4 = og * 16 + wq * 4;
  float acc[4];
#pragma unroll
  for (int i = 0; i < 4; ++i) acc[i] = 0.f;
  const float* wb = Wpw + (size_t)o4 * Cn;
  for (int c = 0; c < Cn; ++c) {
    const float hv = smem[c * 65 + l];
#pragma unroll
    for (int i = 0; i < 4; ++i) acc[i] = fmaf(wb[i * Cn + c], hv, acc[i]);
  }

  // GroupNorm: this wave's 4 o == exactly one GN group (4 ch x 64 l)
  float s1 = acc[0] + acc[1] + acc[2] + acc[3];
  float s2 = acc[0]*acc[0] + acc[1]*acc[1] + acc[2]*acc[2] + acc[3]*acc[3];
#pragma unroll
  for (int m = 32; m > 0; m >>= 1) {
    s1 += __shfl_xor(s1, m, 64);
    s2 += __shfl_xor(s2, m, 64);
  }
  const float mean = s1 * (1.0f / 256.0f);
  const float var  = s2 * (1.0f / 256.0f) - mean * mean;
  const float rstd = rsqrtf(var + 1e-5f);

  float4 res;
  float* rp = (float*)&res;
#pragma unroll
  for (int i = 0; i < 4; ++i) {
    const int o = o4 + i;
    float h = (acc[i] - mean) * rstd;
    h = h * gnw[o] + gnb[o];
    h = 0.5f * h * (1.0f + erff(h * 0.70710678118654752440f));
    rp[i] = h * gates_s[o - og * 16];
  }
  // hh layout (n, l, c): 16B store per thread
  *(float4*)(hh + (size_t)n * CYC * Cn + l * Cn + o4) = res;
}

// ---------------------------------------------------------------------------
// K4a: partial num/den per (b, c) over t-chunk of 64. grid (q=8, b=32).
// ---------------------------------------------------------------------------
__global__ __launch_bounds__(128) void k_dot(const float* __restrict__ x,
    const float* __restrict__ hh, const int* __restrict__ p_idx,
    const float* __restrict__ wv, const float* __restrict__ gamma,
    float* __restrict__ pna, float* __restrict__ pda) {
  const int q = blockIdx.x, b = blockIdx.y;
  const int tid = threadIdx.x;
  const int t0 = q * 64;
  __shared__ unsigned short cycs[64][4];

  const int p0 = p_idx[b * 3 + 0], p1 = p_idx[b * 3 + 1], p2 = p_idx[b * 3 + 2];
  const float w0 = wv[b * 3 + 0], w1 = wv[b * 3 + 1], w2 = wv[b * 3 + 2];
  const float sw = w0 + w1 + w2;
  if (tid < 64) {
    const int t = t0 + tid;
    cycs[tid][0] = (unsigned short)(t / p0);
    cycs[tid][1] = (unsigned short)(t / p1);
    cycs[tid][2] = (unsigned short)(t / p2);
  }
  __syncthreads();

  const int c = tid;
  const float gam = gamma[c];
  const float* hh0 = hh + ((size_t)(b * 3 + 0) * CYC) * Cn + c;
  const float* hh1 = hh + ((size_t)(b * 3 + 1) * CYC) * Cn + c;
  const float* hh2 = hh + ((size_t)(b * 3 + 2) * CYC) * Cn + c;
  const float* xb = x + (size_t)b * Tn * Cn;

  float na = 0.f, da = 0.f;
  for (int tt = 0; tt < 64; ++tt) {
    const int t = t0 + tt;
    const float xv = xb[t * Cn + c];
    const float dv = gam * (w0 * hh0[cycs[tt][0] * Cn] +
                            w1 * hh1[cycs[tt][1] * Cn] +
                            w2 * hh2[cycs[tt][2] * Cn]);
    const float P = sw * xv + dv;
    na += (xv - P) * P;
    da += P * P;
  }
  pna[((size_t)b * 8 + q) * Cn + c] = na;
  pda[((size_t)b * 8 + q) * Cn + c] = da;
}

// ---------------------------------------------------------------------------
// K4b: reduce partials, write out. grid (q=8, b=32).
// ---------------------------------------------------------------------------
__global__ __launch_bounds__(128) void k_out(const float* __restrict__ x,
    const float* __restrict__ hh, const int* __restrict__ p_idx,
    const float* __restrict__ wv, const float* __restrict__ gval,
    const float* __restrict__ gamma, const float* __restrict__ pna,
    const float* __restrict__ pda, float* __restrict__ out) {
  const int q = blockIdx.x, b = blockIdx.y;
  const int tid = threadIdx.x;
  const int t0 = q * 64;
  __shared__ unsigned short cycs[64][4];

  const int p0 = p_idx[b * 3 + 0], p1 = p_idx[b * 3 + 1], p2 = p_idx[b * 3 + 2];
  const float w0 = wv[b * 3 + 0], w1 = wv[b * 3 + 1], w2 = wv[b * 3 + 2];
  const float sw = w0 + w1 + w2;
  const float g = gval[b];
  if (tid < 64) {
    const int t = t0 + tid;
    cycs[tid][0] = (unsigned short)(t / p0);
    cycs[tid][1] = (unsigned short)(t / p1);
    cycs[tid][2] = (unsigned short)(t / p2);
  }
  __syncthreads();

  const int c = tid;
  float num = 0.f, den = 1e-6f;
#pragma unroll
  for (int qq = 0; qq < 8; ++qq) {
    num += pna[((size_t)b * 8 + qq) * Cn + c];
    den += pda[((size_t)b * 8 + qq) * Cn + c];
  }
  const float sc = g * (num / den);

  const float gam = gamma[c];
  const float* hh0 = hh + ((size_t)(b * 3 + 0) * CYC) * Cn + c;
  const float* hh1 = hh + ((size_t)(b * 3 + 1) * CYC) * Cn + c;
  const float* hh2 = hh + ((size_t)(b * 3 + 2) * CYC) * Cn + c;
  const float* xb = x + (size_t)b * Tn * Cn;
  float* ob = out + (size_t)b * Tn * Cn;

  for (int tt = 0; tt < 64; ++tt) {
    const int t = t0 + tt;
    const float xv = xb[t * Cn + c];
    const float dv = gam * (w0 * hh0[cycs[tt][0] * Cn] +
                            w1 * hh1[cycs[tt][1] * Cn] +
                            w2 * hh2[cycs[tt][2] * Cn]);
    const float P = sw * xv + dv;
    ob[t * Cn + c] = xv - sc * P;
  }
}

// ---------------------------------------------------------------------------
extern "C" void kernel_launch(void* const* d_in, const int* in_sizes, int n_in,
                              void* d_out, int out_size, void* d_ws, size_t ws_size,
                              hipStream_t stream) {
  const float* x     = (const float*)d_in[0];
  const float* Wdw   = (const float*)d_in[1];
  const float* Wpw   = (const float*)d_in[2];
  const float* gnw   = (const float*)d_in[3];
  const float* gnb   = (const float*)d_in[4];
  const float* Wgate = (const float*)d_in[5];
  const float* gamma = (const float*)d_in[6];
  float* out = (float*)d_out;

  char* ws = (char*)d_ws;
  int*   p_idx = (int*)ws;                    // 96 ints
  float* wvp   = (float*)(ws + 512);          // 96 floats
  float* gvalp = (float*)(ws + 1024);         // 32 floats
  float* r_ws  = (float*)(ws + 2048);         // 32*57 floats
  float* pna   = (float*)(ws + 10240);        // 32*8*128 floats (128 KB)
  float* pda   = (float*)(ws + 10240 + 131072);
  float* u     = (float*)(ws + 10240 + 262144);                 // 3 MB
  float* hh    = (float*)(ws + 10240 + 262144 + 3145728);       // 3 MB

  k_autocorr<<<Bn * 8, 256, 0, stream>>>(x, r_ws);
  k_topk<<<Bn, 64, 0, stream>>>(r_ws, p_idx, wvp, gvalp);
  k_fold_u<<<dim3(CYC, Bn * Kk), 128, 0, stream>>>(x, p_idx, u);
  k_cycconv<<<dim3(Bn * Kk, 8), 256, 0, stream>>>(u, Wdw, Wpw, gnw, gnb, Wgate, hh);
  k_dot<<<dim3(8, Bn), 128, 0, stream>>>(x, hh, p_idx, wvp, gamma, pna, pda);
  k_out<<<dim3(8, Bn), 128, 0, stream>>>(x, hh, p_idx, wvp, gvalp, gamma, pna, pda, out);
}